// Round 10
// baseline (285.360 us; speedup 1.0000x reference)
//
#include <hip/hip_runtime.h>
#include <math.h>

#define L 64
#define D 512
#define E 8
#define F 256
#define NEG_INF -1e30f

// ---------- proj stage A: partial over 16-wide o-chunks (grid: E*32, 512 thr) ----------
__global__ void projA_kernel(const float* __restrict__ Wk, const float* __restrict__ q,
                             float* __restrict__ part) {
    const int e = blockIdx.x >> 5, oc = blockIdx.x & 31;
    const int d = threadIdx.x;
    const float* wb = Wk + ((size_t)e * D + oc * 16) * D + d;
    const float* qb = q + e * D + oc * 16;
    float acc = 0.f;
    #pragma unroll
    for (int o = 0; o < 16; ++o) acc += wb[(size_t)o * D] * qb[o];
    part[(size_t)blockIdx.x * D + d] = acc;
}

// ---------- prep2: fused proj-combine (blocks 0..7) + trans_W transpose (8..263) ----------
__global__ void prep2_kernel(const float* __restrict__ part, const float* __restrict__ W,
                             float* __restrict__ proj, float* __restrict__ wT) {
    const int b = blockIdx.x;
    if (b < 8) {
        const int i = b * 512 + threadIdx.x;      // i = e*D + d
        const int e = i >> 9, d = i & (D - 1);
        float s = 0.f;
        #pragma unroll
        for (int oc = 0; oc < 32; ++oc) s += part[(size_t)(e * 32 + oc) * D + d];
        proj[i] = s;
    } else {
        const int i = (b - 8) * 512 + threadIdx.x;   // 0..D*F-1
        const int f = i & (F - 1), d = i >> 8;
        wT[(size_t)d * F + f] = W[(size_t)f * D + d];
    }
}

// ---------- gvpv v5: LDS weights, 4-row batch, 4-way interleaved butterflies ----------
// gvpv[v][0..7] = table[v]·gate_W[e];  gvpv[v][8..15] = table[v]·proj[e]

// 4-way interleaved butterfly: four independent shuffle chains overlap in the pipe.
#define RED4(PA, PB, PC, PD)                                        \
    _Pragma("unroll")                                               \
    for (int step = 0; step < 4; ++step) {                          \
        const int mm = 1 << step;                                   \
        const int hh = 8 >> step;                                   \
        const bool hi = (lane & mm) != 0;                           \
        _Pragma("unroll")                                           \
        for (int i = 0; i < 8; ++i) {                               \
            if (i < hh) {                                           \
                float sA = hi ? PA[i] : PA[i + hh];                 \
                float sB = hi ? PB[i] : PB[i + hh];                 \
                float sC = hi ? PC[i] : PC[i + hh];                 \
                float sD = hi ? PD[i] : PD[i + hh];                 \
                float rA = __shfl_xor(sA, mm, 64);                  \
                float rB = __shfl_xor(sB, mm, 64);                  \
                float rC = __shfl_xor(sC, mm, 64);                  \
                float rD = __shfl_xor(sD, mm, 64);                  \
                PA[i] = (hi ? PA[i + hh] : PA[i]) + rA;             \
                PB[i] = (hi ? PB[i + hh] : PB[i]) + rB;             \
                PC[i] = (hi ? PC[i + hh] : PC[i]) + rC;             \
                PD[i] = (hi ? PD[i + hh] : PD[i]) + rD;             \
            }                                                       \
        }                                                           \
    }

__launch_bounds__(256, 2)   // r9-proven: allocator stays spill-free at this budget
__global__ void gvpv_kernel(const float* __restrict__ table,
                            const float* __restrict__ gate_W,
                            const float* __restrict__ proj,
                            float* __restrict__ gvpv, int V, int nwaves) {
    // [t*128 + i]: t=0..7 gate_W rows, t=8..15 proj rows (each row = 128 float4)
    __shared__ float4 wLds[2048];         // 32 KiB
    const int tid  = threadIdx.x;
    const int lane = tid & 63;

    {
        const float4* g4 = (const float4*)gate_W;
        const float4* p4 = (const float4*)proj;
        #pragma unroll
        for (int i = 0; i < 4; ++i) wLds[tid + 256 * i]        = g4[tid + 256 * i];
        #pragma unroll
        for (int i = 0; i < 4; ++i) wLds[1024 + tid + 256 * i] = p4[tid + 256 * i];
    }
    __syncthreads();

    // lane -> output index after bit-reversed butterfly ownership
    const int kout = ((lane & 1) << 3) | ((lane & 2) << 1) | ((lane & 4) >> 1) | ((lane & 8) >> 3);

    const int wid    = (blockIdx.x * blockDim.x + threadIdx.x) >> 6;
    const int stride = 4 * nwaves;

    for (int v = 4 * wid; v + 3 < V; v += stride) {   // V % 4 == 0; 4 contiguous rows = 8 KB
        const float4* rA = (const float4*)(table + (size_t)v * D);
        // issue all 16 global loads up front (8 KB in flight per wave)
        float4 a0 = rA[lane],       a1 = rA[lane + 64];
        float4 b0 = rA[lane + 128], b1 = rA[lane + 192];
        float4 c0 = rA[lane + 256], c1 = rA[lane + 320];
        float4 d0 = rA[lane + 384], d1 = rA[lane + 448];

        float pA[16], pB[16], pC[16], pD[16];
        #pragma unroll
        for (int t = 0; t < 16; ++t) {
            float4 W0 = wLds[t * 128 + lane];
            float4 W1 = wLds[t * 128 + 64 + lane];
            pA[t] = a0.x*W0.x + a0.y*W0.y + a0.z*W0.z + a0.w*W0.w
                  + a1.x*W1.x + a1.y*W1.y + a1.z*W1.z + a1.w*W1.w;
            pB[t] = b0.x*W0.x + b0.y*W0.y + b0.z*W0.z + b0.w*W0.w
                  + b1.x*W1.x + b1.y*W1.y + b1.z*W1.z + b1.w*W1.w;
            pC[t] = c0.x*W0.x + c0.y*W0.y + c0.z*W0.z + c0.w*W0.w
                  + c1.x*W1.x + c1.y*W1.y + c1.z*W1.z + c1.w*W1.w;
            pD[t] = d0.x*W0.x + d0.y*W0.y + d0.z*W0.z + d0.w*W0.w
                  + d1.x*W1.x + d1.y*W1.y + d1.z*W1.z + d1.w*W1.w;
        }

        RED4(pA, pB, pC, pD);
        float fA = pA[0], fB = pB[0], fC = pC[0], fD = pD[0];
        fA += __shfl_xor(fA, 16, 64); fB += __shfl_xor(fB, 16, 64);
        fC += __shfl_xor(fC, 16, 64); fD += __shfl_xor(fD, 16, 64);
        fA += __shfl_xor(fA, 32, 64); fB += __shfl_xor(fB, 32, 64);
        fC += __shfl_xor(fC, 32, 64); fD += __shfl_xor(fD, 32, 64);
        if (lane < 16) {
            gvpv[(size_t)(v    ) * 16 + kout] = fA;
            gvpv[(size_t)(v + 1) * 16 + kout] = fB;
            gvpv[(size_t)(v + 2) * 16 + kout] = fC;
            gvpv[(size_t)(v + 3) * 16 + kout] = fD;
        }
    }
}

// ---------- row2 v2: distributed prefix + all-upfront gather loads ----------
__launch_bounds__(512, 4)   // VGPR <=128: 16 in-flight float4 + acc fits
__global__ void row2_kernel(const int* __restrict__ sample,
                            const float* __restrict__ emb_table,
                            const float* __restrict__ gvpv,
                            const float* __restrict__ gate_b,
                            float* __restrict__ pooled) {
    __shared__ float red[8][D];       // 16 KiB cross-wave reduce
    __shared__ float gpv_s[L][17];    // gv 0..7, pv 8..15, pad (stride 17: conflict-free)
    __shared__ float msk_s[L];
    __shared__ float cf[L];
    __shared__ int   idx_s[L];
    __shared__ float gsc[E];
    __shared__ float cnt_s;
    __shared__ float wsel[2];
    __shared__ int   esel[2];
    __shared__ int   allpad;

    const int tid = threadIdx.x, lane = tid & 63, wv = tid >> 6;
    const int n = blockIdx.x;

    if (wv == 0) {
        // stage per-token gv/pv + mask (64 lanes = 64 tokens)
        int ix = sample[n * L + lane];
        idx_s[lane] = ix;
        float m = (ix != 0) ? 1.f : 0.f;          // PAD==0
        msk_s[lane] = m;
        const float4* gp = (const float4*)(gvpv + (size_t)ix * 16);
        float4 g0 = gp[0], g1 = gp[1], q0 = gp[2], q1 = gp[3];
        gpv_s[lane][0] = g0.x;  gpv_s[lane][1] = g0.y;  gpv_s[lane][2]  = g0.z;  gpv_s[lane][3]  = g0.w;
        gpv_s[lane][4] = g1.x;  gpv_s[lane][5] = g1.y;  gpv_s[lane][6]  = g1.z;  gpv_s[lane][7]  = g1.w;
        gpv_s[lane][8] = q0.x;  gpv_s[lane][9] = q0.y;  gpv_s[lane][10] = q0.z;  gpv_s[lane][11] = q0.w;
        gpv_s[lane][12] = q1.x; gpv_s[lane][13] = q1.y; gpv_s[lane][14] = q1.z;  gpv_s[lane][15] = q1.w;
    }
    __syncthreads();

    // gate reduce: wave wv handles expert wv (8 waves = 8 experts, parallel)
    {
        float v = msk_s[lane] * gpv_s[lane][wv];
        #pragma unroll
        for (int off = 32; off; off >>= 1) v += __shfl_xor(v, off, 64);
        if (lane == 0) gsc[wv] = v * (1.f / 64.f) + gate_b[wv];
        if (wv == 0) {
            float c = msk_s[lane];
            #pragma unroll
            for (int off = 32; off; off >>= 1) c += __shfl_xor(c, off, 64);
            if (lane == 0) cnt_s = c;
        }
    }
    __syncthreads();

    if (tid == 0) {   // top-2, first-index tie-break
        int b0 = 0; float v0 = gsc[0];
        #pragma unroll
        for (int e = 1; e < E; ++e) { if (gsc[e] > v0) { v0 = gsc[e]; b0 = e; } }
        int b1 = -1; float v1 = -3.4e38f;
        #pragma unroll
        for (int e = 0; e < E; ++e) { if (e != b0 && gsc[e] > v1) { v1 = gsc[e]; b1 = e; } }
        float ex = expf(v1 - v0), inv = 1.f / (1.f + ex);
        wsel[0] = inv; wsel[1] = ex * inv;
        esel[0] = b0; esel[1] = b1;
        allpad = (cnt_s == 0.f) ? 1 : 0;
    }
    __syncthreads();

    if (wv == 0) {    // masked softmax over L for the 2 selected experts -> cf
        float m = msk_s[lane];
        float s0 = (m != 0.f) ? gpv_s[lane][8 + esel[0]] : NEG_INF;
        float s1 = (m != 0.f) ? gpv_s[lane][8 + esel[1]] : NEG_INF;
        float m0 = s0, m1 = s1;
        #pragma unroll
        for (int off = 32; off; off >>= 1) {
            m0 = fmaxf(m0, __shfl_xor(m0, off, 64));
            m1 = fmaxf(m1, __shfl_xor(m1, off, 64));
        }
        float e0 = expf(s0 - m0), e1 = expf(s1 - m1);
        float t0 = e0, t1 = e1;
        #pragma unroll
        for (int off = 32; off; off >>= 1) {
            t0 += __shfl_xor(t0, off, 64);
            t1 += __shfl_xor(t1, off, 64);
        }
        float c = wsel[0] * (e0 / t0) + wsel[1] * (e1 / t1);
        cf[lane] = allpad ? 0.f : c;
    }
    __syncthreads();

    // weighted-sum gather: all 16 loads issued up front, then FMAs
    float4 x0[8], x1[8];
    #pragma unroll
    for (int j = 0; j < 8; ++j) {
        const float4* src = (const float4*)(emb_table + (size_t)idx_s[wv * 8 + j] * D);
        x0[j] = src[lane]; x1[j] = src[lane + 64];
    }
    float4 acc0 = {0,0,0,0}, acc1 = {0,0,0,0};
    #pragma unroll
    for (int j = 0; j < 8; ++j) {
        float cj = cf[wv * 8 + j];
        acc0.x += cj*x0[j].x; acc0.y += cj*x0[j].y; acc0.z += cj*x0[j].z; acc0.w += cj*x0[j].w;
        acc1.x += cj*x1[j].x; acc1.y += cj*x1[j].y; acc1.z += cj*x1[j].z; acc1.w += cj*x1[j].w;
    }
    ((float4*)red[wv])[lane]      = acc0;
    ((float4*)red[wv])[lane + 64] = acc1;
    __syncthreads();

    float a = 0.f;
    #pragma unroll
    for (int w = 0; w < 8; ++w) a += red[w][tid];
    pooled[(size_t)n * D + tid] = a;
}

// ---------- out_kernel: gelu(pooled @ wT + b); wave handles 2 rows ----------
__launch_bounds__(256, 4)
__global__ void out_kernel(const float* __restrict__ pooled,
                           const float* __restrict__ wT,     // [D][F]
                           const float* __restrict__ trans_b,
                           float* __restrict__ out) {
    __shared__ float pl[8 * D];             // 16 KiB
    const int tid  = threadIdx.x;
    const int lane = tid & 63;
    const int w    = tid >> 6;              // wave -> rows 2w, 2w+1
    const int n0   = blockIdx.x * 8;

    {
        const float4* src = (const float4*)(pooled + (size_t)n0 * D);
        float4* dst = (float4*)pl;
        #pragma unroll
        for (int i = 0; i < 4; ++i) dst[tid + 256 * i] = src[tid + 256 * i];
    }
    __syncthreads();

    const float* pl0 = pl + (2 * w) * D;
    const float* pl1 = pl0 + D;
    const float4* wT4 = (const float4*)wT;  // [D][F/4]
    float4 acc0 = {0.f,0.f,0.f,0.f}, acc1 = {0.f,0.f,0.f,0.f};
    #pragma unroll 8
    for (int d = 0; d < D; ++d) {
        float4 wt = wT4[d * 64 + lane];     // coalesced 16B/lane, 8 in flight
        float p0 = pl0[d], p1 = pl1[d];     // LDS broadcast
        acc0.x += p0*wt.x; acc0.y += p0*wt.y; acc0.z += p0*wt.z; acc0.w += p0*wt.w;
        acc1.x += p1*wt.x; acc1.y += p1*wt.y; acc1.z += p1*wt.z; acc1.w += p1*wt.w;
    }

    float4 b4 = ((const float4*)trans_b)[lane];
    float4 o0, o1;
    #define GELU(v) (0.5f * (v) * (1.f + erff((v) * 0.70710678118654752f)))
    o0.x = GELU(acc0.x + b4.x); o0.y = GELU(acc0.y + b4.y);
    o0.z = GELU(acc0.z + b4.z); o0.w = GELU(acc0.w + b4.w);
    o1.x = GELU(acc1.x + b4.x); o1.y = GELU(acc1.y + b4.y);
    o1.z = GELU(acc1.z + b4.z); o1.w = GELU(acc1.w + b4.w);
    #undef GELU
    ((float4*)(out + (size_t)(n0 + 2 * w) * F))[lane]     = o0;
    ((float4*)(out + (size_t)(n0 + 2 * w + 1) * F))[lane] = o1;
}

extern "C" void kernel_launch(void* const* d_in, const int* in_sizes, int n_in,
                              void* d_out, int out_size, void* d_ws, size_t ws_size,
                              hipStream_t stream) {
    const int*   sample    = (const int*)d_in[0];
    const float* emb_table = (const float*)d_in[1];
    const float* expert_q  = (const float*)d_in[2];
    const float* expert_Wk = (const float*)d_in[3];
    const float* gate_W    = (const float*)d_in[4];
    const float* gate_b    = (const float*)d_in[5];
    const float* trans_W   = (const float*)d_in[6];
    const float* trans_b   = (const float*)d_in[7];
    float* out = (float*)d_out;

    const int N = in_sizes[0] / L;                 // B*T = 2048
    const int V = in_sizes[1] / D;                 // vocab = 50000

    float* proj   = (float*)d_ws;                  // E*D            = 16 KB
    float* pooled = proj + E * D;                  // N*D            = 4 MB
    float* part   = pooled + (size_t)N * D;        // E*32*D         = 512 KB
    float* wT     = part + E * 32 * D;             // D*F            = 512 KB
    float* gvpv   = wT + (size_t)D * F;            // V*16           = 3.2 MB
    (void)ws_size; (void)n_in; (void)out_size;

    const int GV_BLOCKS = 1024;
    projA_kernel<<<E * 32, D, 0, stream>>>(expert_Wk, expert_q, part);
    prep2_kernel<<<8 + (D * F) / 512, 512, 0, stream>>>(part, trans_W, proj, wT);
    gvpv_kernel<<<GV_BLOCKS, 256, 0, stream>>>(emb_table, gate_W, proj, gvpv, V, GV_BLOCKS * 4);
    row2_kernel<<<N, 512, 0, stream>>>(sample, emb_table, gvpv, gate_b, pooled);
    out_kernel<<<N / 8, 256, 0, stream>>>(pooled, wT, trans_b, out);
}

// Round 11
// 129.373 us; speedup vs baseline: 2.2057x; 2.2057x over previous
//
#include <hip/hip_runtime.h>
#include <math.h>

#define L 64
#define D 512
#define E 8
#define F 256
#define NEG_INF -1e30f

// ---------- proj stage A: partial over 16-wide o-chunks (grid: E*32, 512 thr) ----------
__global__ void projA_kernel(const float* __restrict__ Wk, const float* __restrict__ q,
                             float* __restrict__ part) {
    const int e = blockIdx.x >> 5, oc = blockIdx.x & 31;
    const int d = threadIdx.x;
    const float* wb = Wk + ((size_t)e * D + oc * 16) * D + d;
    const float* qb = q + e * D + oc * 16;
    float acc = 0.f;
    #pragma unroll
    for (int o = 0; o < 16; ++o) acc += wb[(size_t)o * D] * qb[o];
    part[(size_t)blockIdx.x * D + d] = acc;
}

// ---------- prep2: fused proj-combine (blocks 0..7) + trans_W transpose (8..263) ----------
__global__ void prep2_kernel(const float* __restrict__ part, const float* __restrict__ W,
                             float* __restrict__ proj, float* __restrict__ wT) {
    const int b = blockIdx.x;
    if (b < 8) {
        const int i = b * 512 + threadIdx.x;      // i = e*D + d
        const int e = i >> 9, d = i & (D - 1);
        float s = 0.f;
        #pragma unroll
        for (int oc = 0; oc < 32; ++oc) s += part[(size_t)(e * 32 + oc) * D + d];
        proj[i] = s;
    } else {
        const int i = (b - 8) * 512 + threadIdx.x;   // 0..D*F-1
        const int f = i & (F - 1), d = i >> 8;
        wT[(size_t)d * F + f] = W[(size_t)f * D + d];
    }
}

// ---------- warm_kernel: pure sequential read of the table -> L3 residency ----------
// No shuffles, no LDS, no stores. 8 independent loads in flight per thread.
__launch_bounds__(256, 8)
__global__ void warm_kernel(const float4* __restrict__ t4, int n4) {
    const int gid    = blockIdx.x * blockDim.x + threadIdx.x;
    const int stride = gridDim.x * blockDim.x;
    float s0 = 0.f, s1 = 0.f, s2 = 0.f, s3 = 0.f;
    int i = gid;
    for (; i + 7 * stride < n4; i += 8 * stride) {
        float4 v0 = t4[i];              float4 v1 = t4[i + stride];
        float4 v2 = t4[i + 2 * stride]; float4 v3 = t4[i + 3 * stride];
        float4 v4 = t4[i + 4 * stride]; float4 v5 = t4[i + 5 * stride];
        float4 v6 = t4[i + 6 * stride]; float4 v7 = t4[i + 7 * stride];
        s0 += v0.x + v1.y + v2.z + v3.w;
        s1 += v4.x + v5.y + v6.z + v7.w;
        s2 += v0.w + v2.x + v4.y + v6.w;
        s3 += v1.x + v3.z + v5.w + v7.y;
    }
    for (; i < n4; i += stride) {
        float4 v = t4[i];
        s0 += v.x + v.y + v.z + v.w;
    }
    float s = s0 + s1 + s2 + s3;
    asm volatile("" :: "v"(s));          // keep loads alive; nothing stored
}

// ---------- row_kernel (r2-proven): per-row MoE pooling, embeddings in registers ----------
// 512 threads = 8 waves; wave wv owns tokens wv*8..wv*8+7; lane holds 8 floats
// per token (float4 at [lane] and [lane+64] of the 128-float4 row).
__launch_bounds__(512, 4)
__global__ void row_kernel(const int* __restrict__ sample,
                           const float* __restrict__ emb_table,
                           const float* __restrict__ proj,
                           const float* __restrict__ gate_W,
                           const float* __restrict__ gate_b,
                           float* __restrict__ pooled) {
    __shared__ float red[8][D];     // 16 KiB cross-wave reduce buffer
    __shared__ int   idx_s[L];
    __shared__ float msk[L];
    __shared__ float scr[2][L];
    __shared__ float att2[2][L];
    __shared__ float cf[L];
    __shared__ float gred[64];      // 8 waves x 8 experts
    __shared__ float gsc[E];
    __shared__ float wsel[2];
    __shared__ int   esel[2];
    __shared__ int   allpad;

    const int n    = blockIdx.x;
    const int tid  = threadIdx.x;
    const int lane = tid & 63;
    const int wv   = tid >> 6;

    if (tid < L) {
        int ix = sample[n * L + tid];
        idx_s[tid] = ix;
        msk[tid] = (ix != 0) ? 1.f : 0.f;   // PAD==0
    }
    __syncthreads();

    // ---- gather token embeddings into registers ----
    float4 a0[8], a1[8];
    #pragma unroll
    for (int j = 0; j < 8; ++j) {
        const float4* src = (const float4*)(emb_table + (size_t)idx_s[wv * 8 + j] * D);
        a0[j] = src[lane];
        a1[j] = src[lane + 64];
    }

    // ---- gate mean: in-wave partial over 8 tokens, cross-wave via LDS ----
    {
        float4 s0 = {0.f, 0.f, 0.f, 0.f}, s1 = {0.f, 0.f, 0.f, 0.f};
        #pragma unroll
        for (int j = 0; j < 8; ++j) {
            float m = msk[wv * 8 + j];
            s0.x += m * a0[j].x; s0.y += m * a0[j].y; s0.z += m * a0[j].z; s0.w += m * a0[j].w;
            s1.x += m * a1[j].x; s1.y += m * a1[j].y; s1.z += m * a1[j].z; s1.w += m * a1[j].w;
        }
        ((float4*)red[wv])[lane]      = s0;
        ((float4*)red[wv])[lane + 64] = s1;
    }
    __syncthreads();

    float g = 0.f;
    #pragma unroll
    for (int w = 0; w < 8; ++w) g += red[w][tid];
    const float gi = g * (1.f / 64.f);      // exact /64, matches reference mean

    // ---- gate scores ----
    {
        float p[E];
        #pragma unroll
        for (int e = 0; e < E; ++e) p[e] = gi * gate_W[e * D + tid];
        #pragma unroll
        for (int e = 0; e < E; ++e) {
            float v = p[e];
            #pragma unroll
            for (int off = 32; off; off >>= 1) v += __shfl_xor(v, off, 64);
            if (lane == 0) gred[wv * E + e] = v;
        }
    }
    __syncthreads();
    if (tid < E) {
        float s = gate_b[tid];
        #pragma unroll
        for (int w = 0; w < 8; ++w) s += gred[w * E + tid];
        gsc[tid] = s;
    }
    __syncthreads();

    // ---- top-2 + softmax over the two (first-index tie-break like lax.top_k) ----
    if (tid == 0) {
        int b0 = 0; float v0 = gsc[0];
        for (int e = 1; e < E; ++e) if (gsc[e] > v0) { v0 = gsc[e]; b0 = e; }
        int b1 = -1; float v1 = -3.4e38f;
        for (int e = 0; e < E; ++e) if (e != b0 && gsc[e] > v1) { v1 = gsc[e]; b1 = e; }
        float ex  = expf(v1 - v0);
        float inv = 1.f / (1.f + ex);
        wsel[0] = inv; wsel[1] = ex * inv;
        esel[0] = b0;  esel[1] = b1;
        float cnt = 0.f;
        for (int l = 0; l < L; ++l) cnt += msk[l];
        allpad = (cnt == 0.f) ? 1 : 0;
    }
    __syncthreads();

    // ---- score dots for the 2 selected experts (proj rows read direct, L2-hot) ----
    {
        const float4* pe0 = (const float4*)(proj + esel[0] * D);
        const float4* pe1 = (const float4*)(proj + esel[1] * D);
        float4 b00 = pe0[lane], b01 = pe0[lane + 64];
        float4 b10 = pe1[lane], b11 = pe1[lane + 64];
        #pragma unroll
        for (int j = 0; j < 8; ++j) {
            float s0 = a0[j].x*b00.x + a0[j].y*b00.y + a0[j].z*b00.z + a0[j].w*b00.w
                     + a1[j].x*b01.x + a1[j].y*b01.y + a1[j].z*b01.z + a1[j].w*b01.w;
            float s1 = a0[j].x*b10.x + a0[j].y*b10.y + a0[j].z*b10.z + a0[j].w*b10.w
                     + a1[j].x*b11.x + a1[j].y*b11.y + a1[j].z*b11.z + a1[j].w*b11.w;
            #pragma unroll
            for (int off = 32; off; off >>= 1) {
                s0 += __shfl_xor(s0, off, 64);
                s1 += __shfl_xor(s1, off, 64);
            }
            if (lane == 0) {
                int l = wv * 8 + j;
                bool real = (msk[l] != 0.f);
                scr[0][l] = real ? s0 : NEG_INF;
                scr[1][l] = real ? s1 : NEG_INF;
            }
        }
    }
    __syncthreads();

    // ---- masked softmax over L for both selected experts ----
    if (tid < 128) {
        int k = wv;                          // 0 or 1
        float s = scr[k][lane];
        float m = s;
        #pragma unroll
        for (int off = 32; off; off >>= 1) m = fmaxf(m, __shfl_xor(m, off, 64));
        float pex = expf(s - m);
        float sum = pex;
        #pragma unroll
        for (int off = 32; off; off >>= 1) sum += __shfl_xor(sum, off, 64);
        att2[k][lane] = pex / sum;
    }
    __syncthreads();
    if (tid < L) cf[tid] = wsel[0] * att2[0][tid] + wsel[1] * att2[1][tid];
    __syncthreads();

    // ---- pooled: in-wave partial over 8 tokens, cross-wave via LDS ----
    {
        float4 s0 = {0.f, 0.f, 0.f, 0.f}, s1 = {0.f, 0.f, 0.f, 0.f};
        #pragma unroll
        for (int j = 0; j < 8; ++j) {
            float c = cf[wv * 8 + j];
            s0.x += c * a0[j].x; s0.y += c * a0[j].y; s0.z += c * a0[j].z; s0.w += c * a0[j].w;
            s1.x += c * a1[j].x; s1.y += c * a1[j].y; s1.z += c * a1[j].z; s1.w += c * a1[j].w;
        }
        ((float4*)red[wv])[lane]      = s0;
        ((float4*)red[wv])[lane + 64] = s1;
    }
    __syncthreads();

    float acc = 0.f;
    #pragma unroll
    for (int w = 0; w < 8; ++w) acc += red[w][tid];
    if (allpad) acc = 0.f;
    pooled[(size_t)n * D + tid] = acc;
}

// ---------- out_kernel: gelu(pooled @ wT + b); wave handles 2 rows ----------
__launch_bounds__(256, 4)
__global__ void out_kernel(const float* __restrict__ pooled,
                           const float* __restrict__ wT,     // [D][F]
                           const float* __restrict__ trans_b,
                           float* __restrict__ out) {
    __shared__ float pl[8 * D];             // 16 KiB
    const int tid  = threadIdx.x;
    const int lane = tid & 63;
    const int w    = tid >> 6;              // wave -> rows 2w, 2w+1
    const int n0   = blockIdx.x * 8;

    {
        const float4* src = (const float4*)(pooled + (size_t)n0 * D);
        float4* dst = (float4*)pl;
        #pragma unroll
        for (int i = 0; i < 4; ++i) dst[tid + 256 * i] = src[tid + 256 * i];
    }
    __syncthreads();

    const float* pl0 = pl + (2 * w) * D;
    const float* pl1 = pl0 + D;
    const float4* wT4 = (const float4*)wT;  // [D][F/4]
    float4 acc0 = {0.f,0.f,0.f,0.f}, acc1 = {0.f,0.f,0.f,0.f};
    #pragma unroll 4
    for (int d = 0; d < D; ++d) {
        float4 wt = wT4[d * 64 + lane];     // coalesced 16B/lane
        float p0 = pl0[d], p1 = pl1[d];     // LDS broadcast
        acc0.x += p0*wt.x; acc0.y += p0*wt.y; acc0.z += p0*wt.z; acc0.w += p0*wt.w;
        acc1.x += p1*wt.x; acc1.y += p1*wt.y; acc1.z += p1*wt.z; acc1.w += p1*wt.w;
    }

    float4 b4 = ((const float4*)trans_b)[lane];
    float4 o0, o1;
    #define GELU(v) (0.5f * (v) * (1.f + erff((v) * 0.70710678118654752f)))
    o0.x = GELU(acc0.x + b4.x); o0.y = GELU(acc0.y + b4.y);
    o0.z = GELU(acc0.z + b4.z); o0.w = GELU(acc0.w + b4.w);
    o1.x = GELU(acc1.x + b4.x); o1.y = GELU(acc1.y + b4.y);
    o1.z = GELU(acc1.z + b4.z); o1.w = GELU(acc1.w + b4.w);
    #undef GELU
    ((float4*)(out + (size_t)(n0 + 2 * w) * F))[lane]     = o0;
    ((float4*)(out + (size_t)(n0 + 2 * w + 1) * F))[lane] = o1;
}

extern "C" void kernel_launch(void* const* d_in, const int* in_sizes, int n_in,
                              void* d_out, int out_size, void* d_ws, size_t ws_size,
                              hipStream_t stream) {
    const int*   sample    = (const int*)d_in[0];
    const float* emb_table = (const float*)d_in[1];
    const float* expert_q  = (const float*)d_in[2];
    const float* expert_Wk = (const float*)d_in[3];
    const float* gate_W    = (const float*)d_in[4];
    const float* gate_b    = (const float*)d_in[5];
    const float* trans_W   = (const float*)d_in[6];
    const float* trans_b   = (const float*)d_in[7];
    float* out = (float*)d_out;

    const int N = in_sizes[0] / L;                 // B*T = 2048
    const int V = in_sizes[1] / D;                 // vocab = 50000

    float* proj   = (float*)d_ws;                  // E*D       = 16 KB
    float* pooled = proj + E * D;                  // N*D       = 4 MB
    float* part   = pooled + (size_t)N * D;        // E*32*D    = 512 KB
    float* wT     = part + E * 32 * D;             // D*F       = 512 KB
    (void)ws_size; (void)n_in; (void)out_size;

    projA_kernel<<<E * 32, D, 0, stream>>>(expert_Wk, expert_q, part);
    prep2_kernel<<<8 + (D * F) / 512, 512, 0, stream>>>(part, trans_W, proj, wT);
    warm_kernel<<<2048, 256, 0, stream>>>((const float4*)emb_table, V * (D / 4));
    row_kernel<<<N, 512, 0, stream>>>(sample, emb_table, proj, gate_W, gate_b, pooled);
    out_kernel<<<N / 8, 256, 0, stream>>>(pooled, wT, trans_b, out);
}